// Round 5
// baseline (128.932 us; speedup 1.0000x reference)
//
#include <hip/hip_runtime.h>
#include <hip/hip_cooperative_groups.h>
#include <limits.h>

namespace cg = cooperative_groups;

constexpr int HW = 65536;       // 256*256
constexpr int RES_SHIFT = 3;    // RES=8
constexpr int NB = 512;         // 2 blocks/CU -> all co-resident (cooperative)
constexpr int TPB = 256;

__device__ inline float wave_sum(float v) {
#pragma unroll
    for (int o = 32; o > 0; o >>= 1) v += __shfl_down(v, o, 64);
    return v;
}

__device__ inline float sq4(const float4& v) {
    return v.x * v.x + v.y * v.y + v.z * v.z + v.w * v.w;
}

__device__ inline float4 ld4(const float* __restrict__ out, int idx) {
    int b = idx >> 14;          // 16384 float4 per image-channel
    int w = idx & 16383;
    return *reinterpret_cast<const float4*>(
        out + (((size_t)(b * 5 + 4)) << 16) + ((size_t)w << 2));
}

// ws layout (bytes):
//   [0, NB*4)      float partials_all[NB]
//   [4096, ...)    float4 box_p[nbox]
//
// ONE cooperative kernel:
//   * box phase on blocks [0, nbox): per-image flag segment-max is a
//     key-guarded wave-max (K_BOX=64 rows/image, image-major, 64 | n_rows)
//   * bulk sum of output[:,4,:,:]^2, 8x unrolled float4, per-block partial
//   * grid.sync(), then block 0 reduces partials and writes the loss.
__global__ void k_main(const float* __restrict__ out, int total4,
                       const int* __restrict__ labels, int n_rows,
                       float* __restrict__ partials_all,
                       float4* __restrict__ box_p,
                       int Bm1, float* __restrict__ outp) {
    const int nbox = (n_rows + TPB - 1) / TPB;
    const bool boxblk = blockIdx.x < (unsigned)nbox;

    // ---- box phase: issue scattered loads EARLY (overlap with bulk loop)
    bool bvalid = false;
    float o0 = 0, o1 = 0, o2 = 0, o3 = 0, o4 = 0;
    float vx = 0, vy = 0, ax = 0, ay = 0;
    if (boxblk) {
        int r = blockIdx.x * TPB + threadIdx.x;
        bool inb = r < n_rows;
        int flag = INT_MIN, img = -7, x = 0, y = 0;
        if (inb) {
            const int* L = labels + (size_t)r * 10;
            x = L[0]; y = L[1];
            vx = (float)L[4]; vy = (float)L[5];
            ax = (float)L[6]; ay = (float)L[7];
            flag = L[8]; img = L[9];
        }
        int f = flag;
#pragma unroll
        for (int o = 1; o < 64; o <<= 1) {
            int of = __shfl_xor(f, o, 64);
            int ok = __shfl_xor(img, o, 64);
            if (ok == img) f = max(f, of);
        }
        if (inb && img >= 1 && f != -1) {
            bvalid = true;
            int b = img - 1;
            int xc = x >> RES_SHIFT;
            int yc = y >> RES_SHIFT;
            size_t base = (((size_t)(b * 5)) << 16) + ((size_t)yc << 8) + (size_t)xc;
            o0 = out[base];
            o1 = out[base + HW];
            o2 = out[base + 2 * (size_t)HW];
            o3 = out[base + 3 * (size_t)HW];
            o4 = out[base + 4 * (size_t)HW];
        }
    }

    // ---- bulk pass: channel 4, 8x unrolled independent float4 loads
    float acc = 0.0f;
    const int S = gridDim.x * blockDim.x;
    int idx = blockIdx.x * blockDim.x + threadIdx.x;
    for (; idx + 7 * S < total4; idx += 8 * S) {
        float4 v[8];
#pragma unroll
        for (int j = 0; j < 8; ++j) v[j] = ld4(out, idx + j * S);
#pragma unroll
        for (int j = 0; j < 8; ++j) acc += sq4(v[j]);
    }
    for (; idx < total4; idx += S) acc += sq4(ld4(out, idx));

    __shared__ float s[4];
    acc = wave_sum(acc);
    if ((threadIdx.x & 63) == 0) s[threadIdx.x >> 6] = acc;
    __syncthreads();
    if (threadIdx.x == 0)
        partials_all[blockIdx.x] = s[0] + s[1] + s[2] + s[3];

    // ---- box reduction (block-uniform branch)
    if (boxblk) {
        float vel = 0, acl = 0, osq = 0, cnt = 0;
        if (bvalid) {
            vel = (o0 - vx) * (o0 - vx) + (o1 - vy) * (o1 - vy);
            acl = (o2 - ax) * (o2 - ax) + (o3 - ay) * (o3 - ay);
            osq = o4 * o4;
            cnt = 1.0f;
        }
        osq = wave_sum(osq);
        vel = wave_sum(vel);
        acl = wave_sum(acl);
        cnt = wave_sum(cnt);
        __shared__ float sb[4][4];
        if ((threadIdx.x & 63) == 0) {
            int wv = threadIdx.x >> 6;
            sb[wv][0] = osq; sb[wv][1] = vel; sb[wv][2] = acl; sb[wv][3] = cnt;
        }
        __syncthreads();
        if (threadIdx.x == 0) {
            box_p[blockIdx.x] = make_float4(sb[0][0] + sb[1][0] + sb[2][0] + sb[3][0],
                                            sb[0][1] + sb[1][1] + sb[2][1] + sb[3][1],
                                            sb[0][2] + sb[1][2] + sb[2][2] + sb[3][2],
                                            sb[0][3] + sb[1][3] + sb[2][3] + sb[3][3]);
        }
    }

    // ---- grid-wide barrier, then block 0 finalizes
    __threadfence();
    cg::this_grid().sync();
    if (blockIdx.x != 0) return;

    float all = 0.0f, osq = 0.0f, vel = 0.0f, acl = 0.0f, cnt = 0.0f;
    for (int i = threadIdx.x; i < NB; i += TPB) all += partials_all[i];
    if (threadIdx.x < nbox) {
        float4 p = box_p[threadIdx.x];
        osq = p.x; vel = p.y; acl = p.z; cnt = p.w;
    }
    all = wave_sum(all); osq = wave_sum(osq); vel = wave_sum(vel);
    acl = wave_sum(acl); cnt = wave_sum(cnt);
    __shared__ float sf[4][5];
    int lane = threadIdx.x & 63, wv = threadIdx.x >> 6;
    if (lane == 0) {
        sf[wv][0] = all; sf[wv][1] = osq; sf[wv][2] = vel; sf[wv][3] = acl; sf[wv][4] = cnt;
    }
    __syncthreads();
    if (threadIdx.x == 0) {
        for (int i = 1; i < 4; ++i) {
            all += sf[i][0]; osq += sf[i][1]; vel += sf[i][2];
            acl += sf[i][3]; cnt += sf[i][4];
        }
        float n_obj = cnt;
        float total = (float)Bm1 * (float)HW;
        float n_noobj = total - n_obj;
        float noobj_loss = (all - osq) / fmaxf(n_noobj, 1.0f);
        float vel_loss = vel / fmaxf(2.0f * n_obj, 1.0f);
        float accel_loss = acl / fmaxf(2.0f * n_obj, 1.0f);
        float full = 0.5f * noobj_loss + vel_loss + accel_loss;
        outp[0] = (n_obj == 0.0f) ? (0.5f * noobj_loss) : full;
    }
}

extern "C" void kernel_launch(void* const* d_in, const int* in_sizes, int n_in,
                              void* d_out, int out_size, void* d_ws, size_t ws_size,
                              hipStream_t stream) {
    const float* output = (const float*)d_in[0];
    const int* labels = (const int*)d_in[1];

    int Bm1 = in_sizes[0] / (5 * HW);      // 128
    int n_rows = in_sizes[1] / 10;         // 8256
    int total4 = Bm1 * (HW / 4);           // 2,097,152 float4

    char* ws = (char*)d_ws;
    float* partials_all = (float*)ws;                   // NB floats
    float4* box_p = (float4*)(ws + 4096);               // nbox float4
    float* outp = (float*)d_out;

    void* args[] = { (void*)&output, (void*)&total4, (void*)&labels,
                     (void*)&n_rows, (void*)&partials_all, (void*)&box_p,
                     (void*)&Bm1, (void*)&outp };
    hipLaunchCooperativeKernel((void*)k_main, dim3(NB), dim3(TPB),
                               args, 0, stream);
}

// Round 6
// 15.106 us; speedup vs baseline: 8.5353x; 8.5353x over previous
//
#include <hip/hip_runtime.h>
#include <limits.h>

constexpr int HW = 65536;       // 256*256
constexpr int RES_SHIFT = 3;    // RES=8
constexpr int NB = 1024;        // bulk-pass blocks: total4 / (NB*TPB) == 8 exactly
constexpr int TPB = 256;

__device__ inline float wave_sum(float v) {
#pragma unroll
    for (int o = 32; o > 0; o >>= 1) v += __shfl_down(v, o, 64);
    return v;
}

__device__ inline float sq4(const float4& v) {
    return v.x * v.x + v.y * v.y + v.z * v.z + v.w * v.w;
}

__device__ inline float4 ld4(const float* __restrict__ out, int idx) {
    int b = idx >> 14;          // 16384 float4 per image-channel
    int w = idx & 16383;
    return *reinterpret_cast<const float4*>(
        out + (((size_t)(b * 5 + 4)) << 16) + ((size_t)w << 2));
}

// ws layout (bytes):
//   [0    , 4096)           float4 box_p[nbox]      (33 * 16 B)
//   [4096 , 4096 + NB*4)    float  partials_all[NB]

// Fused kernel: bulk sum of output[:,4,:,:]^2 (8x-unrolled independent
// float4 loads, per-block partials, no atomics) + box phase on blocks
// [0, nbox). Per-image flag segment-max is a key-guarded wave-max
// (K_BOX=64 rows/image, image-major, 64 | n_rows).
__global__ void k_main(const float* __restrict__ out, int total4,
                       const int* __restrict__ labels, int n_rows,
                       float* __restrict__ partials_all,
                       float4* __restrict__ box_p) {
    const int nbox = (n_rows + TPB - 1) / TPB;
    const bool boxblk = blockIdx.x < (unsigned)nbox;

    // ---- box phase: issue scattered loads EARLY (overlap with bulk loop)
    bool bvalid = false;
    float o0 = 0, o1 = 0, o2 = 0, o3 = 0, o4 = 0;
    float vx = 0, vy = 0, ax = 0, ay = 0;
    if (boxblk) {
        int r = blockIdx.x * TPB + threadIdx.x;
        bool inb = r < n_rows;
        int flag = INT_MIN, img = -7, x = 0, y = 0;
        if (inb) {
            const int* L = labels + (size_t)r * 10;
            x = L[0]; y = L[1];
            vx = (float)L[4]; vy = (float)L[5];
            ax = (float)L[6]; ay = (float)L[7];
            flag = L[8]; img = L[9];
        }
        int f = flag;
#pragma unroll
        for (int o = 1; o < 64; o <<= 1) {
            int of = __shfl_xor(f, o, 64);
            int ok = __shfl_xor(img, o, 64);
            if (ok == img) f = max(f, of);
        }
        if (inb && img >= 1 && f != -1) {
            bvalid = true;
            int b = img - 1;
            int xc = x >> RES_SHIFT;
            int yc = y >> RES_SHIFT;
            size_t base = (((size_t)(b * 5)) << 16) + ((size_t)yc << 8) + (size_t)xc;
            o0 = out[base];
            o1 = out[base + HW];
            o2 = out[base + 2 * (size_t)HW];
            o3 = out[base + 3 * (size_t)HW];
            o4 = out[base + 4 * (size_t)HW];
        }
    }

    // ---- bulk pass: channel 4, 8 independent float4 loads in flight
    float acc = 0.0f;
    const int S = gridDim.x * blockDim.x;
    int idx = blockIdx.x * blockDim.x + threadIdx.x;
    for (; idx + 7 * S < total4; idx += 8 * S) {
        float4 v[8];
#pragma unroll
        for (int j = 0; j < 8; ++j) v[j] = ld4(out, idx + j * S);
#pragma unroll
        for (int j = 0; j < 8; ++j) acc += sq4(v[j]);
    }
    for (; idx < total4; idx += S) acc += sq4(ld4(out, idx));

    __shared__ float s[4];
    acc = wave_sum(acc);
    if ((threadIdx.x & 63) == 0) s[threadIdx.x >> 6] = acc;
    __syncthreads();
    if (threadIdx.x == 0)
        partials_all[blockIdx.x] = s[0] + s[1] + s[2] + s[3];

    // ---- box reduction (block-uniform branch)
    if (boxblk) {
        float vel = 0, acl = 0, osq = 0, cnt = 0;
        if (bvalid) {
            vel = (o0 - vx) * (o0 - vx) + (o1 - vy) * (o1 - vy);
            acl = (o2 - ax) * (o2 - ax) + (o3 - ay) * (o3 - ay);
            osq = o4 * o4;
            cnt = 1.0f;
        }
        osq = wave_sum(osq);
        vel = wave_sum(vel);
        acl = wave_sum(acl);
        cnt = wave_sum(cnt);
        __shared__ float sb[4][4];
        if ((threadIdx.x & 63) == 0) {
            int wv = threadIdx.x >> 6;
            sb[wv][0] = osq; sb[wv][1] = vel; sb[wv][2] = acl; sb[wv][3] = cnt;
        }
        __syncthreads();
        if (threadIdx.x == 0) {
            box_p[blockIdx.x] = make_float4(sb[0][0] + sb[1][0] + sb[2][0] + sb[3][0],
                                            sb[0][1] + sb[1][1] + sb[2][1] + sb[3][1],
                                            sb[0][2] + sb[1][2] + sb[2][2] + sb[3][2],
                                            sb[0][3] + sb[1][3] + sb[2][3] + sb[3][3]);
        }
    }
}

__global__ void k_final(const float* __restrict__ partials_all,
                        const float4* __restrict__ box_p,
                        int nb, int nbox, int Bm1, float* __restrict__ outp) {
    float all = 0.0f, osq = 0.0f, vel = 0.0f, acl = 0.0f, cnt = 0.0f;
    for (int i = threadIdx.x; i < nb; i += blockDim.x) all += partials_all[i];
    for (int i = threadIdx.x; i < nbox; i += blockDim.x) {
        float4 p = box_p[i];
        osq += p.x; vel += p.y; acl += p.z; cnt += p.w;
    }
    all = wave_sum(all); osq = wave_sum(osq); vel = wave_sum(vel);
    acl = wave_sum(acl); cnt = wave_sum(cnt);
    __shared__ float s[4][5];
    int lane = threadIdx.x & 63, wv = threadIdx.x >> 6;
    if (lane == 0) {
        s[wv][0] = all; s[wv][1] = osq; s[wv][2] = vel; s[wv][3] = acl; s[wv][4] = cnt;
    }
    __syncthreads();
    if (threadIdx.x == 0) {
        for (int i = 1; i < 4; ++i) {
            all += s[i][0]; osq += s[i][1]; vel += s[i][2]; acl += s[i][3]; cnt += s[i][4];
        }
        float n_obj = cnt;
        float total = (float)Bm1 * (float)HW;
        float n_noobj = total - n_obj;
        float noobj_loss = (all - osq) / fmaxf(n_noobj, 1.0f);
        float vel_loss = vel / fmaxf(2.0f * n_obj, 1.0f);
        float accel_loss = acl / fmaxf(2.0f * n_obj, 1.0f);
        float full = 0.5f * noobj_loss + vel_loss + accel_loss;
        outp[0] = (n_obj == 0.0f) ? (0.5f * noobj_loss) : full;
    }
}

extern "C" void kernel_launch(void* const* d_in, const int* in_sizes, int n_in,
                              void* d_out, int out_size, void* d_ws, size_t ws_size,
                              hipStream_t stream) {
    const float* output = (const float*)d_in[0];
    const int* labels = (const int*)d_in[1];

    int Bm1 = in_sizes[0] / (5 * HW);      // 128
    int n_rows = in_sizes[1] / 10;         // 8256
    int total4 = Bm1 * (HW / 4);           // 2,097,152 float4
    int nbox = (n_rows + TPB - 1) / TPB;   // 33

    char* ws = (char*)d_ws;
    float4* box_p = (float4*)ws;                        // 33 * 16 B
    float* partials_all = (float*)(ws + 4096);          // NB floats

    k_main<<<NB, TPB, 0, stream>>>(output, total4, labels, n_rows,
                                   partials_all, box_p);
    k_final<<<1, 256, 0, stream>>>(partials_all, box_p, NB, nbox, Bm1, (float*)d_out);
}